// Round 1
// 620.015 us; speedup vs baseline: 1.0522x; 1.0522x over previous
//
#include <hip/hip_runtime.h>

// InferenceAttention: B=16, N=16 @ start=2048, D=4096, H=32, HK=8, DH=128,
// CTX=4096, T_end=2064. fp32 in/out. bf16 MFMA 16x16x32 everywhere.
//
// R4: weights are no longer pre-transposed. k_gemm stages B by fused
// gather-transpose-convert from the original fp32 [k][n] layout (coalesced
// scalar column-gather, read exactly ONCE: 160 MB total vs 400 MB before).
// BM=256 tile removes the bm-duplicated B reads. Attention V transpose now
// dh-major gather + conflict-free ds_write_b64 (was 16x 4-way b16 stores).
//
// ws:
//   xb     @ 0MB    bf16 [256][4096]            2MB
//   qpart  @ 82MB   fp32 [4][256][6144]         25MB
//   zb     @ 108MB  bf16 [256][4096]            2MB
//   zpO    @ 110MB  bf16 [4][256][4096]         8MB
//   zpL    @ 118MB  fp32 [4][16][32][16]        128KB
//   opart  @ 119MB  fp32 [4][256][4096]         16MB
//   qbf    @ 136MB  bf16 [256][4096]            2MB    (roped+scaled Q)

#define CTX 4096

typedef __attribute__((ext_vector_type(8))) short short8;
typedef __attribute__((ext_vector_type(4))) float f32x4;

__device__ __forceinline__ unsigned short f2bf(float f) {
  union { float f; unsigned u; } a; a.f = f;
  unsigned r = a.u + 0x7FFFu + ((a.u >> 16) & 1u);   // RNE, finite only
  return (unsigned short)(r >> 16);
}

__device__ __forceinline__ f32x4 mfma_bf16(short8 a, short8 b, f32x4 c) {
  return __builtin_amdgcn_mfma_f32_16x16x32_bf16(a, b, c, 0, 0, 0);
}

// async global->LDS, 16B/lane; LDS dest = wave-uniform base + lane*16
__device__ __forceinline__ void gll16(const unsigned short* g, unsigned short* l) {
  __builtin_amdgcn_global_load_lds(
      (__attribute__((address_space(1))) unsigned int*)(g),
      (__attribute__((address_space(3))) unsigned int*)(l), 16, 0, 0);
}

// ---------------- prep: x fp32 -> bf16 only (weights consumed in-place by GEMM) ----------------
__global__ __launch_bounds__(256) void k_prepx(const float* __restrict__ x,
                                               unsigned short* __restrict__ xb)
{
  int e4 = blockIdx.x * 256 + threadIdx.x;   // 262144 float4
  float4 v = ((const float4*)x)[e4];
  ushort4 o; o.x = f2bf(v.x); o.y = f2bf(v.y); o.z = f2bf(v.z); o.w = f2bf(v.w);
  ((ushort4*)xb)[e4] = o;
}

// ---------------- GEMM: Cp[4][256][Ntot] = A[256][4096] @ W[4096][Ntot]
// BM=256 x BN=64 tile, BK=64, K-split 4 (blockIdx.y). 4 waves, wave = 64m x 64n,
// acc 4x4. A (bf16 [m][k]) via gll16; B (fp32 [k][n]) fused gather-transpose:
// thread t owns n=t&63, k-span [(t>>6)*16,+16): 16 coalesced scalar loads
// (64 lanes = 256B contiguous per step), f2bf, 2x ds_write_b128 to [n][k+pad].
__global__ __launch_bounds__(256) void k_gemm(const unsigned short* __restrict__ A,
    const float* __restrict__ w0, const float* __restrict__ w1,
    const float* __restrict__ w2, float* __restrict__ Cp, int Ntot, int qkv)
{
  __shared__ unsigned short sA[256 * 64];   // [m][k] linear (gll16 dest)
  __shared__ unsigned short sB[64 * 72];    // [n][k], pad 64->72 (16B-aligned rows)
  const int tid = threadIdx.x;
  const int w = tid >> 6, lane = tid & 63, quad = lane >> 4, l16 = lane & 15;
  const int bn = blockIdx.x, ks = blockIdx.y;
  const int r8 = lane >> 3, c8 = (lane & 7) << 3;

  const float* src; int N, nloc;
  if (qkv && bn >= 64) {
    if (bn < 80) { src = w1; N = 1024; nloc = (bn - 64) << 6; }   // wk
    else         { src = w2; N = 1024; nloc = (bn - 80) << 6; }   // wv
  } else         { src = w0; N = 4096; nloc = bn << 6; }          // wq / wo

  const unsigned short* Ab = A + (ks << 10);
  const float* Wb = src + (size_t)(ks << 10) * N + nloc;
  const int gn = tid & 63, gk = (tid >> 6) << 4;

  f32x4 acc[4][4];
#pragma unroll
  for (int mf = 0; mf < 4; ++mf)
#pragma unroll
    for (int nf = 0; nf < 4; ++nf) acc[mf][nf] = (f32x4){0.f, 0.f, 0.f, 0.f};

  for (int kt = 0; kt < 16; ++kt) {
#pragma unroll
    for (int i = 0; i < 8; ++i)             // A: wave w stages rows [w*64, +64)
      gll16(Ab + (size_t)(w * 64 + i * 8 + r8) * 4096 + kt * 64 + c8,
            &sA[(w * 64 + i * 8) * 64]);
    {                                       // B: gather-transpose-convert
      const float* s0 = Wb + (size_t)(kt * 64 + gk) * N + gn;
      short8 lo, hi;
#pragma unroll
      for (int j = 0; j < 8; ++j) lo[j] = (short)f2bf(s0[(size_t)j * N]);
#pragma unroll
      for (int j = 0; j < 8; ++j) hi[j] = (short)f2bf(s0[(size_t)(j + 8) * N]);
      *(short8*)&sB[gn * 72 + gk]     = lo;
      *(short8*)&sB[gn * 72 + gk + 8] = hi;
    }
    __syncthreads();
#pragma unroll
    for (int kk = 0; kk < 2; ++kk) {
      short8 af[4], bfr[4];
#pragma unroll
      for (int mf = 0; mf < 4; ++mf)
        af[mf] = *(const short8*)&sA[(w * 64 + mf * 16 + l16) * 64 + kk * 32 + quad * 8];
#pragma unroll
      for (int nf = 0; nf < 4; ++nf)
        bfr[nf] = *(const short8*)&sB[(nf * 16 + l16) * 72 + kk * 32 + quad * 8];
#pragma unroll
      for (int mf = 0; mf < 4; ++mf)
#pragma unroll
        for (int nf = 0; nf < 4; ++nf)
          acc[mf][nf] = mfma_bf16(af[mf], bfr[nf], acc[mf][nf]);
    }
    __syncthreads();
  }

  float* Cz = Cp + (size_t)ks * 256 * Ntot + bn * 64;
#pragma unroll
  for (int mf = 0; mf < 4; ++mf)
#pragma unroll
    for (int nf = 0; nf < 4; ++nf)
#pragma unroll
      for (int r = 0; r < 4; ++r)
        Cz[(size_t)(w * 64 + mf * 16 + quad * 4 + r) * Ntot + nf * 16 + l16]
            = acc[mf][nf][r];
}

// ---------------- finalize QKV: sum 4 K-split partials; rope Q,K; scatter KV; bf16 Q ----------------
__global__ __launch_bounds__(256) void k_kvfin(const float* __restrict__ qp,
    const float* __restrict__ fcos, const float* __restrict__ fsin,
    float* __restrict__ ck, float* __restrict__ cv, unsigned short* __restrict__ qbf)
{
  const float scale = 0.08838834764831845f; // 1/sqrt(128)
  const size_t PS = (size_t)256 * 6144;     // partial stride
  int id = blockIdx.x * 256 + threadIdx.x;
  if (id < 524288) {                        // Q: 256 rows x 32h x 64fi pairs
    int m = id >> 11, pc = id & 2047;
    int h = pc >> 6, fi = pc & 63, npos = m & 15;
    size_t off = (size_t)m * 6144 + h * 128 + 2 * fi;
    float a = 0.f, b2 = 0.f;
#pragma unroll
    for (int s = 0; s < 4; ++s) { a += qp[s * PS + off]; b2 += qp[s * PS + off + 1]; }
    float c = fcos[npos * 64 + fi], sn = fsin[npos * 64 + fi];
    unsigned short o0 = f2bf((a * c - b2 * sn) * scale);
    unsigned short o1 = f2bf((a * sn + b2 * c) * scale);
    qbf[(size_t)m * 4096 + h * 128 + 2 * fi]     = o0;
    qbf[(size_t)m * 4096 + h * 128 + 2 * fi + 1] = o1;
  } else if (id < 655360) {                 // K: 256 rows x 8hk x 64fi pairs
    int e = id - 524288;
    int m = e >> 9, pc = e & 511;
    int hk = pc >> 6, fi = pc & 63;
    int b = m >> 4, npos = m & 15;
    size_t off = (size_t)m * 6144 + 4096 + hk * 128 + 2 * fi;
    float a = 0.f, b2 = 0.f;
#pragma unroll
    for (int s = 0; s < 4; ++s) { a += qp[s * PS + off]; b2 += qp[s * PS + off + 1]; }
    float c = fcos[npos * 64 + fi], sn = fsin[npos * 64 + fi];
    float* dst = ck + ((size_t)(b * 8 + hk) * CTX + 2048 + npos) * 128 + 2 * fi;
    dst[0] = a * c - b2 * sn;
    dst[1] = a * sn + b2 * c;
  } else {                                  // V: 256 rows x 1024 cols
    int e = id - 655360;
    int m = e >> 10, cc = e & 1023;
    int b = m >> 4, npos = m & 15;
    int hk = cc >> 7, dh = cc & 127;
    size_t off = (size_t)m * 6144 + 5120 + cc;
    float a = 0.f;
#pragma unroll
    for (int s = 0; s < 4; ++s) a += qp[s * PS + off];
    cv[((size_t)(b * 8 + hk) * CTX + 2048 + npos) * 128 + dh] = a;
  }
}

// ---------------- attention: 512 blocks = (b, hk, T-quarter); waves = 4 GQA reps ----------------
__global__ __launch_bounds__(256) void k_attn(const unsigned short* __restrict__ qbf,
    const float* __restrict__ ck, const float* __restrict__ cv,
    unsigned short* __restrict__ zpO, float* __restrict__ zpL)
{
  __shared__ unsigned short Ks[32][136];    // [t][dh] bf16, pad 128->136
  __shared__ unsigned short Vs[128][36];    // [dh][t] bf16, pad 32->36 (8B rows, CF b64)
  __shared__ unsigned short Ps[4][16][40];  // per-wave P relayout [w][npos][t]

  const int tid = threadIdx.x;
  const int w = tid >> 6, lane = tid & 63, quad = lane >> 4, l16 = lane & 15;
  const int bid = blockIdx.x;
  const int split = bid & 3, hk = (bid >> 2) & 7, b = bid >> 5;
  const int h = hk * 4 + w;

  // Q fragments: pre-roped/scaled bf16, A-layout (l16 = npos)
  short8 qf[4];
  {
    const unsigned short* qrow = qbf + (size_t)(b * 16 + l16) * 4096 + h * 128;
#pragma unroll
    for (int kf = 0; kf < 4; ++kf)
      qf[kf] = *(const short8*)(qrow + kf * 32 + quad * 8);
  }

  const float* Kg = ck + (size_t)(b * 8 + hk) * CTX * 128;
  const float* Vg = cv + (size_t)(b * 8 + hk) * CTX * 128;
  const int tb = split * 512;
  const int NT = (split == 3) ? 17 : 16;    // split 3 covers [1536,2080), tail masked

  f32x4 O[8];
#pragma unroll
  for (int df = 0; df < 8; ++df) O[df] = (f32x4){0.f, 0.f, 0.f, 0.f};
  float lp[4] = {0.f, 0.f, 0.f, 0.f};

  // K: thread u -> (trow=u>>5, c4=u&31): float4, t-major rows (linear layout).
  // V: thread u -> (dh=u&127, tq=u>>7): 4 t-strided scalars at fixed dh
  //    (64 lanes = 256B contiguous per step) -> ushort4 at Vs[dh][tq*4].
  float4 pk[4]; float pv[16];
#define A_LOAD(IT_) do { \
    _Pragma("unroll") for (int i = 0; i < 4; ++i) { \
      int u = tid + (i << 8); int trow = u >> 5, c4 = u & 31; \
      pk[i] = *(const float4*)(Kg + (size_t)(tb + (IT_) * 32 + trow) * 128 + c4 * 4); \
    } \
    _Pragma("unroll") for (int i = 0; i < 4; ++i) { \
      int u = tid + (i << 8); int dh = u & 127, tq = u >> 7; \
      _Pragma("unroll") for (int j = 0; j < 4; ++j) \
        pv[i * 4 + j] = Vg[(size_t)(tb + (IT_) * 32 + tq * 4 + j) * 128 + dh]; \
    } } while (0)
#define A_STORE() do { \
    _Pragma("unroll") for (int i = 0; i < 4; ++i) { \
      int u = tid + (i << 8); int trow = u >> 5, c4 = u & 31; \
      ushort4 k4; k4.x = f2bf(pk[i].x); k4.y = f2bf(pk[i].y); \
      k4.z = f2bf(pk[i].z); k4.w = f2bf(pk[i].w); \
      *(ushort4*)&Ks[trow][c4 * 4] = k4; \
    } \
    _Pragma("unroll") for (int i = 0; i < 4; ++i) { \
      int u = tid + (i << 8); int dh = u & 127, tq = u >> 7; \
      ushort4 v4; v4.x = f2bf(pv[i * 4 + 0]); v4.y = f2bf(pv[i * 4 + 1]); \
      v4.z = f2bf(pv[i * 4 + 2]); v4.w = f2bf(pv[i * 4 + 3]); \
      *(ushort4*)&Vs[dh][tq * 4] = v4; \
    } } while (0)

  A_LOAD(0);
  A_STORE();
  __syncthreads();

  for (int it = 0; it < NT; ++it) {
    if (it + 1 < NT) A_LOAD(it + 1);

    f32x4 S0 = (f32x4){0.f,0.f,0.f,0.f}, S1 = (f32x4){0.f,0.f,0.f,0.f};
#pragma unroll
    for (int kf = 0; kf < 4; ++kf) {
      short8 k0 = *(const short8*)&Ks[l16][kf * 32 + quad * 8];
      short8 k1 = *(const short8*)&Ks[16 + l16][kf * 32 + quad * 8];
      S0 = mfma_bf16(qf[kf], k0, S0);
      S1 = mfma_bf16(qf[kf], k1, S1);
    }

    const bool lastT = (split == 3) && (it == 16);  // t in [2048,2080)
    float p0[4], p1[4];
#pragma unroll
    for (int r = 0; r < 4; ++r) {
      int row = quad * 4 + r;
      if (!lastT) { p0[r] = __expf(S0[r]); p1[r] = __expf(S1[r]); }
      else        { p0[r] = (l16 <= row) ? __expf(S0[r]) : 0.f; p1[r] = 0.f; }
      lp[r] += p0[r] + p1[r];
      Ps[w][row][l16]      = f2bf(p0[r]);
      Ps[w][row][16 + l16] = f2bf(p1[r]);
    }

    short8 pf = *(const short8*)&Ps[w][l16][quad * 8];
#pragma unroll
    for (int df = 0; df < 8; ++df) {
      short8 vb = *(const short8*)&Vs[df * 16 + l16][quad * 8];
      O[df] = mfma_bf16(pf, vb, O[df]);
    }

    __syncthreads();
    if (it + 1 < NT) A_STORE();
    __syncthreads();
  }
#undef A_LOAD
#undef A_STORE

#pragma unroll
  for (int r = 0; r < 4; ++r)
#pragma unroll
    for (int off = 1; off < 16; off <<= 1) lp[r] += __shfl_xor(lp[r], off);

#pragma unroll
  for (int df = 0; df < 8; ++df)
#pragma unroll
    for (int r = 0; r < 4; ++r)
      zpO[(size_t)(split * 256 + b * 16 + quad * 4 + r) * 4096 + h * 128 + df * 16 + l16]
          = f2bf(O[df][r]);

  if (l16 == 0) {
#pragma unroll
    for (int r = 0; r < 4; ++r)
      zpL[((split * 16 + b) * 32 + h) * 16 + quad * 4 + r] = lp[r];
  }
}

// ---------------- combine 4 T-splits, normalize, emit bf16 z ----------------
__global__ __launch_bounds__(256) void k_combine(const unsigned short* __restrict__ zpO,
    const float* __restrict__ zpL, unsigned short* __restrict__ zb)
{
  int e = blockIdx.x * 256 + threadIdx.x;   // < 1048576
  int m = e >> 12, col = e & 4095;
  int b = m >> 4, npos = m & 15, h = col >> 7;
  float num = 0.f, den = 0.f;
#pragma unroll
  for (int s = 0; s < 4; ++s) {
    union { unsigned u; float f; } cv2;
    cv2.u = (unsigned)zpO[(size_t)s * 1048576 + e] << 16;
    num += cv2.f;
    den += zpL[((s * 16 + b) * 32 + h) * 16 + npos];
  }
  zb[e] = f2bf(num / den);
}

// ---------------- sum 4 oproj K-split partials -> fp32 out ----------------
__global__ __launch_bounds__(256) void k_fin(const float* __restrict__ op,
                                             float* __restrict__ out)
{
  int e4 = blockIdx.x * 256 + threadIdx.x;  // 262144 float4
  float4 o = ((const float4*)op)[e4];
#pragma unroll
  for (int s = 1; s < 4; ++s) {
    float4 p = ((const float4*)(op + (size_t)s * 1048576))[e4];
    o.x += p.x; o.y += p.y; o.z += p.z; o.w += p.w;
  }
  ((float4*)out)[e4] = o;
}

extern "C" void kernel_launch(void* const* d_in, const int* in_sizes, int n_in,
                              void* d_out, int out_size, void* d_ws, size_t ws_size,
                              hipStream_t stream) {
  const float* x  = (const float*)d_in[0];
  const float* fc = (const float*)d_in[1];
  const float* fs = (const float*)d_in[2];
  float* ck = (float*)d_in[4];
  float* cv = (float*)d_in[5];
  const float* wq = (const float*)d_in[6];
  const float* wk = (const float*)d_in[7];
  const float* wv = (const float*)d_in[8];
  const float* wo = (const float*)d_in[9];
  float* out = (float*)d_out;

  char* ws = (char*)d_ws;
#define MB(x) ((size_t)(x) << 20)
  unsigned short* xb    = (unsigned short*)(ws);
  float*          qpart = (float*)(ws + MB(82));
  unsigned short* zb    = (unsigned short*)(ws + MB(108));
  unsigned short* zpO   = (unsigned short*)(ws + MB(110));
  float*          zpL   = (float*)(ws + MB(118));
  float*          opart = (float*)(ws + MB(119));
  unsigned short* qbf   = (unsigned short*)(ws + MB(136));
#undef MB

  k_prepx<<<1024, 256, 0, stream>>>(x, xb);
  k_gemm<<<dim3(96, 4), 256, 0, stream>>>(xb, wq, wk, wv, qpart, 6144, 1);
  k_kvfin<<<3584, 256, 0, stream>>>(qpart, fc, fs, ck, cv, qbf);
  k_attn<<<512, 256, 0, stream>>>(qbf, ck, cv, zpO, zpL);
  k_combine<<<4096, 256, 0, stream>>>(zpO, zpL, zb);
  k_gemm<<<dim3(64, 4), 256, 0, stream>>>(zb, wo, wo, wo, opart, 4096, 0);
  k_fin<<<1024, 256, 0, stream>>>(opart, out);
}